// Round 5
// baseline (550.471 us; speedup 1.0000x reference)
//
#include <hip/hip_runtime.h>
#include <math.h>

#define K_EMB 1024
#define D_DIM 256
#define T_SZ 2048
#define TOT 16777216        // B*D*T
#define LOSS_OFF 16777216
#define IDX_OFF 16777217
#define NDC 17              // 16 real d-chunks + 1 esq-fold chunk (A-side)
#define MARGIN 0.04f        // s-space refine margin (~11 sigma of fp16-hi dot err)

typedef __attribute__((ext_vector_type(8)))  _Float16 half8;
typedef __attribute__((ext_vector_type(8)))  short    s16x8;
typedef __attribute__((ext_vector_type(16))) float    f32x16;
typedef __attribute__((ext_vector_type(4)))  float    f32x4;

// top-3 insert, maximizing, tie -> smaller k (numpy first-occurrence argmin).
// Order-independent selection: strict > plus k-tie gives same result any scan order.
__device__ __forceinline__ void ins3(float& v1, int& k1, float& v2, int& k2,
                                     float& v3, int& k3, float v, int k) {
    bool b1 = (v > v1) || (v == v1 && k < k1);
    bool b2 = (v > v2) || (v == v2 && k < k2);
    bool b3 = (v > v3) || (v == v3 && k < k3);
    if (b1) { v3 = v2; k3 = k2; v2 = v1; k2 = k1; v1 = v; k1 = k; }
    else if (b2) { v3 = v2; k3 = k2; v2 = v; k2 = k; }
    else if (b3) { v3 = v; k3 = k; }
}

// --- Kernel 0: per-code squared norms (fp32) ------------------------------
__global__ __launch_bounds__(256) void esq_kernel(const float* __restrict__ E,
                                                  float* __restrict__ esq) {
    int k = blockIdx.x * 4 + (threadIdx.x >> 6);
    int lane = threadIdx.x & 63;
    const float* er = E + (size_t)k * D_DIM;
    float s = 0.f;
#pragma unroll
    for (int i = 0; i < 4; ++i) { float v = er[lane + 64 * i]; s = fmaf(v, v, s); }
#pragma unroll
    for (int off = 32; off > 0; off >>= 1) s += __shfl_down(s, off, 64);
    if (lane == 0) esq[k] = s;
}

// --- Kernel 0b: pre-pack E -> MFMA A-frag order, split fp16 hi/lo ---------
// frag (kc 0..32, dc 0..17, lane): A[m=lane&31][kd=(lane>>5)*8+j],
// k = kc*32+m, d = dc*16+(lane>>5)*8+j. dc==16 = esq-fold: hi[j0]=h, lo[j0]=l,
// h+l ~= -0.5*esq[k] (residual ~1e-5), paired with B-fold=1.0 at j0/dhalf0.
__global__ __launch_bounds__(256) void prepack_kernel(const float* __restrict__ E,
        const float* __restrict__ esq, unsigned short* __restrict__ Ehi,
        unsigned short* __restrict__ Elo) {
    int gid = blockIdx.x * 256 + threadIdx.x;        // == (kc*17+dc)*64 + lane
    if (gid >= 32 * NDC * 64) return;
    int lane = gid & 63;
    int dc = (gid >> 6) % NDC;
    int kc = gid / (NDC * 64);
    int m = lane & 31, dh = lane >> 5;
    int k = kc * 32 + m;
    half8 hv, lv;
#pragma unroll
    for (int j = 0; j < 8; ++j) { hv[j] = (_Float16)0.f; lv[j] = (_Float16)0.f; }
    if (dc < 16) {
        int d0 = dc * 16 + dh * 8;
        const float* ep = E + (size_t)k * D_DIM + d0;
#pragma unroll
        for (int j = 0; j < 8; ++j) {
            float e = ep[j];
            _Float16 h = (_Float16)e;                // RNE
            hv[j] = h;
            lv[j] = (_Float16)(e - (float)h);
        }
    } else if (dh == 0) {
        float v = -0.5f * esq[k];
        _Float16 h = (_Float16)v;
        hv[0] = h;
        lv[0] = (_Float16)(v - (float)h);
    }
    ((s16x8*)Ehi)[gid] = __builtin_bit_cast(s16x8, hv);
    ((s16x8*)Elo)[gid] = __builtin_bit_cast(s16x8, lv);
}

// --- Kernel 1: argmin via fp16 2-term MFMA + fp64 near-tie refine ---------
// 256 thr / 4 waves, t-tile 64 (2 tc), grid 1024 (all co-resident: 39 KB LDS,
// 128-reg budget -> 4 blocks/CU). Wave w owns kc [8w, 8w+8) via 4 passes of
// 2 kc; acc[2kc][2tc] = 64 AGPRs. D[row=k%32][col=t%32], col=lane&31.
__global__ __launch_bounds__(256, 4) void argmin_f16_kernel(
        const float* __restrict__ X, const unsigned short* __restrict__ Ehi,
        const unsigned short* __restrict__ Elo, const float* __restrict__ E,
        float* __restrict__ idxf_out) {
    __shared__ s16x8 xf[2 * 16 * 2 * 32];        // 32 KB: [tc][dc][h][m]
    __shared__ float redv[4][2][32][3];          // 3 KB
    __shared__ int   redk[4][2][32][3];          // 3 KB

    int tid = threadIdx.x;
    int n0 = blockIdx.x << 6;                    // 64 rows per block
    int b = n0 >> 11;                            // / T_SZ
    int t0 = n0 & (T_SZ - 1);

    // ---- stage X tile [64 t][256 d] -> fp16-hi frags in LDS ----
    {
        int t = tid & 63, dblk = tid >> 6;       // 4 dblks x 64 d
        int tc = t >> 5, m = t & 31;
        const float* xp = X + (size_t)b * ((size_t)D_DIM * T_SZ) + t0 + t;
        for (int g = 0; g < 8; ++g) {
            int d0 = dblk * 64 + g * 8;
            half8 hv;
#pragma unroll
            for (int j = 0; j < 8; ++j)
                hv[j] = (_Float16)xp[(size_t)(d0 + j) * T_SZ];
            int dc = d0 >> 4, h = (d0 >> 3) & 1;
            xf[((tc * 16 + dc) * 2 + h) * 32 + m] = __builtin_bit_cast(s16x8, hv);
        }
    }
    __syncthreads();

    int lane = tid & 63;
    int w = tid >> 6;
    int mrow = lane & 31;
    int dhalf = lane >> 5;

    const s16x8* ehp = (const s16x8*)Ehi;
    const s16x8* elp = (const s16x8*)Elo;

    half8 bfold;
#pragma unroll
    for (int j = 0; j < 8; ++j) bfold[j] = (_Float16)0.f;
    if (dhalf == 0) bfold[0] = (_Float16)1.f;    // B=1.0 at k-slot 256 only

    for (int p = 0; p < 4; ++p) {
        int kcb = w * 8 + p * 2;                 // this pass's kc pair
        f32x16 a00, a01, a10, a11;               // acc[kci][tc]
#pragma unroll
        for (int i = 0; i < 16; ++i) { a00[i] = 0.f; a01[i] = 0.f;
                                       a10[i] = 0.f; a11[i] = 0.f; }
#pragma unroll 2
        for (int dc = 0; dc < 16; ++dc) {
            size_t e0 = ((size_t)kcb * NDC + dc) * 64 + lane;
            half8 ah0 = __builtin_bit_cast(half8, ehp[e0]);
            half8 al0 = __builtin_bit_cast(half8, elp[e0]);
            half8 ah1 = __builtin_bit_cast(half8, ehp[e0 + NDC * 64]);
            half8 al1 = __builtin_bit_cast(half8, elp[e0 + NDC * 64]);
            half8 b0 = __builtin_bit_cast(half8, xf[((0 * 16 + dc) * 2 + dhalf) * 32 + mrow]);
            half8 b1 = __builtin_bit_cast(half8, xf[((1 * 16 + dc) * 2 + dhalf) * 32 + mrow]);
            a00 = __builtin_amdgcn_mfma_f32_32x32x16_f16(ah0, b0, a00, 0, 0, 0);
            a00 = __builtin_amdgcn_mfma_f32_32x32x16_f16(al0, b0, a00, 0, 0, 0);
            a01 = __builtin_amdgcn_mfma_f32_32x32x16_f16(ah0, b1, a01, 0, 0, 0);
            a01 = __builtin_amdgcn_mfma_f32_32x32x16_f16(al0, b1, a01, 0, 0, 0);
            a10 = __builtin_amdgcn_mfma_f32_32x32x16_f16(ah1, b0, a10, 0, 0, 0);
            a10 = __builtin_amdgcn_mfma_f32_32x32x16_f16(al1, b0, a10, 0, 0, 0);
            a11 = __builtin_amdgcn_mfma_f32_32x32x16_f16(ah1, b1, a11, 0, 0, 0);
            a11 = __builtin_amdgcn_mfma_f32_32x32x16_f16(al1, b1, a11, 0, 0, 0);
        }
        {   // esq-fold chunk (A dc==16, B constant)
            size_t e0 = ((size_t)kcb * NDC + 16) * 64 + lane;
            half8 ah0 = __builtin_bit_cast(half8, ehp[e0]);
            half8 al0 = __builtin_bit_cast(half8, elp[e0]);
            half8 ah1 = __builtin_bit_cast(half8, ehp[e0 + NDC * 64]);
            half8 al1 = __builtin_bit_cast(half8, elp[e0 + NDC * 64]);
            a00 = __builtin_amdgcn_mfma_f32_32x32x16_f16(ah0, bfold, a00, 0, 0, 0);
            a00 = __builtin_amdgcn_mfma_f32_32x32x16_f16(al0, bfold, a00, 0, 0, 0);
            a01 = __builtin_amdgcn_mfma_f32_32x32x16_f16(ah0, bfold, a01, 0, 0, 0);
            a01 = __builtin_amdgcn_mfma_f32_32x32x16_f16(al0, bfold, a01, 0, 0, 0);
            a10 = __builtin_amdgcn_mfma_f32_32x32x16_f16(ah1, bfold, a10, 0, 0, 0);
            a10 = __builtin_amdgcn_mfma_f32_32x32x16_f16(al1, bfold, a10, 0, 0, 0);
            a11 = __builtin_amdgcn_mfma_f32_32x32x16_f16(ah1, bfold, a11, 0, 0, 0);
            a11 = __builtin_amdgcn_mfma_f32_32x32x16_f16(al1, bfold, a11, 0, 0, 0);
        }
        // scan -> per-tc top3, merge lane^32, fold into LDS slot (own slot, no race)
#pragma unroll
        for (int tc = 0; tc < 2; ++tc) {
            float v1 = -INFINITY, v2 = -INFINITY, v3 = -INFINITY;
            int k1 = 0, k2 = 0, k3 = 0;
#pragma unroll
            for (int kci = 0; kci < 2; ++kci) {
                const f32x16& a = (tc == 0) ? (kci == 0 ? a00 : a10)
                                            : (kci == 0 ? a01 : a11);
                int kb = (kcb + kci) * 32 + 4 * dhalf;
#pragma unroll
                for (int r = 0; r < 16; ++r) {
                    int kk = kb + (r & 3) + 8 * (r >> 2);
                    ins3(v1, k1, v2, k2, v3, k3, a[r], kk);
                }
            }
            float pv1 = __shfl_xor(v1, 32, 64); int pk1 = __shfl_xor(k1, 32, 64);
            float pv2 = __shfl_xor(v2, 32, 64); int pk2 = __shfl_xor(k2, 32, 64);
            float pv3 = __shfl_xor(v3, 32, 64); int pk3 = __shfl_xor(k3, 32, 64);
            ins3(v1, k1, v2, k2, v3, k3, pv1, pk1);
            ins3(v1, k1, v2, k2, v3, k3, pv2, pk2);
            ins3(v1, k1, v2, k2, v3, k3, pv3, pk3);
            if (dhalf == 0) {
                if (p > 0) {
#pragma unroll
                    for (int j = 0; j < 3; ++j)
                        ins3(v1, k1, v2, k2, v3, k3,
                             redv[w][tc][mrow][j], redk[w][tc][mrow][j]);
                }
                redv[w][tc][mrow][0] = v1; redk[w][tc][mrow][0] = k1;
                redv[w][tc][mrow][1] = v2; redk[w][tc][mrow][1] = k2;
                redv[w][tc][mrow][2] = v3; redk[w][tc][mrow][2] = k3;
            }
        }
    }
    __syncthreads();

    // per-t final reduce across 4 waves + refine + write
    if (tid < 64) {
        int t = tid, tc = t >> 5, m = t & 31;
        float v1 = -INFINITY, v2 = -INFINITY, v3 = -INFINITY;
        int k1 = 0, k2 = 0, k3 = 0;
#pragma unroll
        for (int ww = 0; ww < 4; ++ww)
#pragma unroll
            for (int j = 0; j < 3; ++j)
                ins3(v1, k1, v2, k2, v3, k3, redv[ww][tc][m][j], redk[ww][tc][m][j]);
        int kbest = k1;
        int cand[3]; int nc = 1; cand[0] = k1;
        if (v2 >= v1 - MARGIN) cand[nc++] = k2;
        if (v3 >= v1 - MARGIN) cand[nc++] = k3;
        if (nc > 1) {   // near-tie: exact fp64 distances over all in-margin cands
            const float* xc = X + (size_t)b * ((size_t)D_DIM * T_SZ) + t0 + t;
            double best = 1.0e300; int kb = 0x7FFFFFFF;
            for (int i = 0; i < nc; ++i) {
                int ks = cand[i];
                const float* ep = E + (size_t)ks * D_DIM;
                double d2 = 0.0;
                for (int d = 0; d < D_DIM; ++d) {
                    double u = (double)xc[(size_t)d * T_SZ] - (double)ep[d];
                    d2 += u * u;
                }
                if (d2 < best || (d2 == best && ks < kb)) { best = d2; kb = ks; }
            }
            kbest = kb;
        }
        idxf_out[n0 + t] = (float)kbest;         // FLOAT value (out buffer is fp32)
    }
}

// --- Kernel 2: gather quantized, write out0 [B,D,T], commitment loss ------
// 32-t tile, 256 thr, 33 KB LDS -> 4 blocks/CU. Staging: lane-linear row
// copies (conflict-free, coalesced). Out: float4 over t; q reads ~2-way free.
__global__ __launch_bounds__(256) void gather_kernel(const float* __restrict__ X,
        const float* __restrict__ E, const float* __restrict__ idxf_in,
        float* __restrict__ out0, float* __restrict__ loss) {
    __shared__ float q[32 * 257];
    __shared__ int idxs[32];
    __shared__ float lred[4];
    int tid = threadIdx.x;
    int b = blockIdx.x >> 6;
    int t0 = (blockIdx.x & 63) << 5;
    if (tid < 32) idxs[tid] = (int)idxf_in[(size_t)b * T_SZ + t0 + tid];
    __syncthreads();
    for (int rr = 0; rr < 32; ++rr)              // idxs[rr] uniform -> s_load base
        q[rr * 257 + tid] = E[(size_t)idxs[rr] * D_DIM + tid];
    __syncthreads();
    int tq = tid & 7, d0 = tid >> 3;             // 8 t-quads x 32 d
    float lsum = 0.f;
    for (int it = 0; it < 8; ++it) {
        int d = d0 + it * 32;
        size_t off = (size_t)b * ((size_t)D_DIM * T_SZ) + (size_t)d * T_SZ + t0 + tq * 4;
        f32x4 xv = *(const f32x4*)(X + off);
        f32x4 qv;
#pragma unroll
        for (int c = 0; c < 4; ++c) qv[c] = q[(tq * 4 + c) * 257 + d];
        *(f32x4*)(out0 + off) = qv;              // STE: x + (q-x) == q
#pragma unroll
        for (int c = 0; c < 4; ++c) {
            float df = qv[c] - xv[c];
            lsum = fmaf(df, df, lsum);
        }
    }
#pragma unroll
    for (int off = 32; off > 0; off >>= 1) lsum += __shfl_down(lsum, off, 64);
    int w = tid >> 6;
    if ((tid & 63) == 0) lred[w] = lsum;
    __syncthreads();
    if (tid == 0)
        atomicAdd(loss, (lred[0] + lred[1] + lred[2] + lred[3]) * (0.5f / (float)TOT));
}

extern "C" void kernel_launch(void* const* d_in, const int* in_sizes, int n_in,
                              void* d_out, int out_size, void* d_ws, size_t ws_size,
                              hipStream_t stream) {
    const float* X = (const float*)d_in[0];   // [32, 256, 2048] fp32
    const float* E = (const float*)d_in[1];   // [1024, 256] fp32
    float* out = (float*)d_out;
    float* loss = out + LOSS_OFF;
    float* idxf = out + IDX_OFF;

    float* esq = (float*)d_ws;                                   // 4 KB
    unsigned short* Ehi = (unsigned short*)((char*)d_ws + 4096); // 544 KB
    unsigned short* Elo = (unsigned short*)((char*)d_ws + 4096 + 32 * NDC * 64 * 8 * 2);

    hipMemsetAsync(loss, 0, sizeof(float), stream);
    esq_kernel<<<K_EMB / 4, 256, 0, stream>>>(E, esq);
    prepack_kernel<<<(32 * NDC * 64 + 255) / 256, 256, 0, stream>>>(E, esq, Ehi, Elo);
    argmin_f16_kernel<<<1024, 256, 0, stream>>>(X, Ehi, Elo, E, idxf);
    gather_kernel<<<2048, 256, 0, stream>>>(X, E, idxf, out, loss);
}